// Round 1
// baseline (3606.120 us; speedup 1.0000x reference)
//
#include <hip/hip_runtime.h>
#include <hip/hip_fp16.h>

// ---------------------------------------------------------------------------
// Problem constants
// ---------------------------------------------------------------------------
#define BB 512
#define TT 128
#define DD 1024
#define HH 1024
#define VV 256
#define SS 26

typedef _Float16 half8 __attribute__((ext_vector_type(8)));
typedef _Float16 half4 __attribute__((ext_vector_type(4)));
typedef float f32x4 __attribute__((ext_vector_type(4)));

// ---------------------------------------------------------------------------
// async global -> LDS, 16 B per lane. LDS dest must be wave-uniform base +
// lane*16 (it is: all our staging layouts are linear in tid).
// ---------------------------------------------------------------------------
__device__ __forceinline__ void cp16(const void* g, void* l) {
    __builtin_amdgcn_global_load_lds(
        (const __attribute__((address_space(1))) void*)g,
        (__attribute__((address_space(3))) void*)l, 16, 0, 0);
}

// ---------------------------------------------------------------------------
// fast device math
// ---------------------------------------------------------------------------
__device__ __forceinline__ float tanh_fast(float x) {
    float ex = __expf(2.f * x);
    return 1.f - 2.f * __builtin_amdgcn_rcpf(ex + 1.f);
}
__device__ __forceinline__ float sigmoid_fast(float x) {
    return __builtin_amdgcn_rcpf(1.f + __expf(-x));
}

// ---------------------------------------------------------------------------
// f32 -> f16 conversion, 4 elements/thread
// ---------------------------------------------------------------------------
__global__ void cvt_f32_to_f16_v4(const float* __restrict__ src,
                                  _Float16* __restrict__ dst, long n4) {
    long i = (long)blockIdx.x * blockDim.x + threadIdx.x;
    long stride = (long)gridDim.x * blockDim.x;
    for (; i < n4; i += stride) {
        float4 v = ((const float4*)src)[i];
        half4 h;
        h[0] = (_Float16)v.x; h[1] = (_Float16)v.y;
        h[2] = (_Float16)v.z; h[3] = (_Float16)v.w;
        ((half4*)dst)[i] = h;
    }
}

// Gate-interleaved concatenated LSTM weight:
// col c: g=c>>6, q=(c>>4)&3, jl=c&15 -> orig row q*1024+g*16+jl
__global__ void build_wcatp(const float* __restrict__ W_ih,
                            const float* __restrict__ W_hh,
                            _Float16* __restrict__ wcatp) {
    int idx = blockIdx.x * 256 + threadIdx.x;
    int c = idx >> 11;
    int k = idx & 2047;
    int g = c >> 6, q = (c >> 4) & 3, jl = c & 15;
    int row = q * 1024 + g * 16 + jl;
    float v = (k < 1024) ? W_ih[(size_t)row * 1280 + k]
                         : W_hh[(size_t)row * 1024 + (k - 1024)];
    wcatp[idx] = (_Float16)v;
}

// onehT[v][g] = W_ih[g][1024+v]   (fp32, gate-major)
__global__ void build_onehT(const float* __restrict__ W_ih,
                            float* __restrict__ onehT) {
    int idx = blockIdx.x * 256 + threadIdx.x;
    int v = idx >> 12;
    int g = idx & 4095;
    onehT[idx] = W_ih[(size_t)g * 1280 + 1024 + v];
}

__global__ void build_bsum(const float* __restrict__ b_ih,
                           const float* __restrict__ b_hh,
                           float* __restrict__ bsum) {
    int i = blockIdx.x * 256 + threadIdx.x;
    bsum[i] = b_ih[i] + b_hh[i];
}

// ---------------------------------------------------------------------------
// GEMM 128x128: C[M,N] = A[M,K]*B[N,K]^T (+bias). fp16 in, f32 acc.
// Min-2-phase double-buffer: issue next-tile global_load_lds BEFORE the
// ds_read+MFMA of the current tile; one barrier per K-step (drain at end).
// K must be a multiple of 64 (true for all call sites: 1024 / 2048).
// MODE 1: f16 out. MODE 2: logits remap (m -> s=m/512,b=m%512) f32 out.
// SWZ 1: XCD row-grouping swizzle (gridDim.y % 8 == 0).
// ---------------------------------------------------------------------------
template <int MODE, int SWZ>
__global__ __launch_bounds__(256) void gemm_bt(
    const _Float16* __restrict__ A, int lda,
    const _Float16* __restrict__ B, int ldb,
    void* __restrict__ Cp, int ldc, int K, const float* __restrict__ bias) {
    __shared__ __align__(16) _Float16 As[2][128 * 32];
    __shared__ __align__(16) _Float16 Bs[2][128 * 32];

    int bx = blockIdx.x, by = blockIdx.y;
    if (SWZ) {
        int nx = gridDim.x;
        int bid = by * nx + bx;
        int xcd = bid & 7;
        int local = bid >> 3;
        int rows_per_xcd = gridDim.y >> 3;
        bx = local % nx;
        by = xcd * rows_per_xcd + local / nx;
    }
    const int tid  = threadIdx.x;
    const int lane = tid & 63;
    const int wid  = tid >> 6;
    const int wm   = wid >> 1;
    const int wn   = wid & 1;
    const int m0 = by * 128;
    const int n0 = bx * 128;

    f32x4 acc[4][4];
#pragma unroll
    for (int i = 0; i < 4; ++i)
#pragma unroll
        for (int j = 0; j < 4; ++j)
            acc[i][j] = (f32x4){0.f, 0.f, 0.f, 0.f};

    const int row0 = tid >> 2;
    const int ch0  = tid & 3;
    const _Float16* a0 = A + (size_t)(m0 + row0) * lda + ch0 * 8;
    const _Float16* a1 = A + (size_t)(m0 + row0 + 64) * lda + ch0 * 8;
    const _Float16* b0 = B + (size_t)(n0 + row0) * ldb + ch0 * 8;
    const _Float16* b1 = B + (size_t)(n0 + row0 + 64) * ldb + ch0 * 8;

    const int la = lane & 15;
    const int kc = (lane >> 4) * 8;

    auto stage = [&](int buf, int k0) {
        cp16(a0 + k0, &As[buf][tid * 8]);
        cp16(a1 + k0, &As[buf][64 * 32 + tid * 8]);
        cp16(b0 + k0, &Bs[buf][tid * 8]);
        cp16(b1 + k0, &Bs[buf][64 * 32 + tid * 8]);
    };
    auto compute = [&](int buf) {
        half8 af[4], bf[4];
#pragma unroll
        for (int mt = 0; mt < 4; ++mt)
            af[mt] = *(const half8*)(&As[buf][(wm * 64 + mt * 16 + la) * 32 + kc]);
#pragma unroll
        for (int nt = 0; nt < 4; ++nt)
            bf[nt] = *(const half8*)(&Bs[buf][(wn * 64 + nt * 16 + la) * 32 + kc]);
#pragma unroll
        for (int mt = 0; mt < 4; ++mt)
#pragma unroll
            for (int nt = 0; nt < 4; ++nt)
                acc[mt][nt] = __builtin_amdgcn_mfma_f32_16x16x32_f16(
                    af[mt], bf[nt], acc[mt][nt], 0, 0, 0);
    };

    stage(0, 0);
    __syncthreads();                     // buf0 ready
    for (int k0 = 0; k0 < K; k0 += 64) {
        stage(1, k0 + 32);               // k0+32 <= K-32, always valid
        compute(0);
        __syncthreads();                 // drains stage(1); buf0 reads done
        if (k0 + 64 < K) stage(0, k0 + 64);
        compute(1);
        __syncthreads();
    }

#pragma unroll
    for (int mt = 0; mt < 4; ++mt) {
#pragma unroll
        for (int nt = 0; nt < 4; ++nt) {
            int gn = n0 + wn * 64 + nt * 16 + la;
            float bv = bias ? bias[gn] : 0.f;
#pragma unroll
            for (int r = 0; r < 4; ++r) {
                int gm = m0 + wm * 64 + mt * 16 + (lane >> 4) * 4 + r;
                float v = acc[mt][nt][r] + bv;
                if (MODE == 1) {
                    ((_Float16*)Cp)[(size_t)gm * ldc + gn] = (_Float16)v;
                } else {
                    int s = gm >> 9;
                    int b = gm & 511;
                    ((float*)Cp)[((size_t)b * SS + s) * VV + gn] = v;
                }
            }
        }
    }
}

// ---------------------------------------------------------------------------
// proj_h = h @ h2h^T + b : tile 16(M) x 64(N), grid (16,32) = 512 blocks
// (2 blocks/CU so barrier drains overlap across blocks). dbuf prefetch loop.
// 4 waves, wave w owns cols w*16..w*16+15 -> one 16x16x32 MFMA per K-step.
// ---------------------------------------------------------------------------
__global__ __launch_bounds__(256) void gemm_ph(
    const _Float16* __restrict__ A, int lda,
    const _Float16* __restrict__ B, int ldb,
    float* __restrict__ C, int ldc, int K, const float* __restrict__ bias) {
    __shared__ __align__(16) _Float16 As[2][16 * 32];
    __shared__ __align__(16) _Float16 Bs[2][64 * 32];
    const int tid  = threadIdx.x;
    const int lane = tid & 63;
    const int wid  = tid >> 6;
    const int m0 = blockIdx.y * 16;
    const int n0 = blockIdx.x * 64;
    const int row = tid >> 2;
    const int ch  = tid & 3;
    const _Float16* ag = A + (size_t)(m0 + (row & 15)) * lda + ch * 8;
    const _Float16* bg = B + (size_t)(n0 + row) * ldb + ch * 8;
    f32x4 acc = (f32x4){0.f, 0.f, 0.f, 0.f};
    const int la = lane & 15;
    const int kc = (lane >> 4) * 8;

    auto stage = [&](int buf, int k0) {
        if (tid < 64) cp16(ag + k0, &As[buf][tid * 8]);
        cp16(bg + k0, &Bs[buf][tid * 8]);
    };
    auto compute = [&](int buf) {
        half8 af = *(const half8*)(&As[buf][la * 32 + kc]);
        half8 bf = *(const half8*)(&Bs[buf][(wid * 16 + la) * 32 + kc]);
        acc = __builtin_amdgcn_mfma_f32_16x16x32_f16(af, bf, acc, 0, 0, 0);
    };

    stage(0, 0);
    __syncthreads();
    for (int k0 = 0; k0 < K; k0 += 64) {
        stage(1, k0 + 32);
        compute(0);
        __syncthreads();
        if (k0 + 64 < K) stage(0, k0 + 64);
        compute(1);
        __syncthreads();
    }

    int gn = n0 + wid * 16 + la;
    float bv = bias[gn];
    int gm0 = m0 + (lane >> 4) * 4;
#pragma unroll
    for (int r = 0; r < 4; ++r)
        C[(size_t)(gm0 + r) * ldc + gn] = acc[r] + bv;
}

// ---------------------------------------------------------------------------
// gates GEMM over gate-interleaved wcatp + fused LSTM pointwise epilogue.
// 64x128 tile, dbuf prefetch loop (K=2048, multiple of 64).
// ---------------------------------------------------------------------------
__global__ __launch_bounds__(256) void gemm_gates(
    const _Float16* __restrict__ A,      // acat [B,2048]
    const _Float16* __restrict__ B,      // wcatp [4096,2048]
    const float* __restrict__ bsum,      // [4096] gate-major
    const float* __restrict__ onehT,     // [V,4096] gate-major
    const int* __restrict__ text,        // [B,SS]
    int step,
    float* __restrict__ c,               // [B,H]
    _Float16* __restrict__ acat,         // [B,2048] (h -> cols 1024:2048)
    _Float16* __restrict__ hid) {        // [SS,B,H]
    __shared__ __align__(16) _Float16 As[2][64 * 32];
    __shared__ __align__(16) _Float16 Bs[2][128 * 32];
    const int tid  = threadIdx.x;
    const int lane = tid & 63;
    const int wid  = tid >> 6;
    const int wm   = wid >> 1;
    const int wn   = wid & 1;
    const int m0 = blockIdx.y * 64;
    const int n0 = blockIdx.x * 128;
    const int K  = 2048;

    f32x4 acc[2][4];
#pragma unroll
    for (int i = 0; i < 2; ++i)
#pragma unroll
        for (int j = 0; j < 4; ++j)
            acc[i][j] = (f32x4){0.f, 0.f, 0.f, 0.f};

    const int row0 = tid >> 2;
    const int ch0  = tid & 3;
    const _Float16* ag  = A + (size_t)(m0 + row0) * 2048 + ch0 * 8;
    const _Float16* bg0 = B + (size_t)(n0 + row0) * 2048 + ch0 * 8;
    const _Float16* bg1 = B + (size_t)(n0 + row0 + 64) * 2048 + ch0 * 8;
    const int la = lane & 15;
    const int kc = (lane >> 4) * 8;

    auto stage = [&](int buf, int k0) {
        cp16(ag + k0, &As[buf][tid * 8]);
        cp16(bg0 + k0, &Bs[buf][tid * 8]);
        cp16(bg1 + k0, &Bs[buf][64 * 32 + tid * 8]);
    };
    auto compute = [&](int buf) {
        half8 af[2], bf[4];
#pragma unroll
        for (int mt = 0; mt < 2; ++mt)
            af[mt] = *(const half8*)(&As[buf][(wm * 32 + mt * 16 + la) * 32 + kc]);
#pragma unroll
        for (int nt = 0; nt < 4; ++nt)
            bf[nt] = *(const half8*)(&Bs[buf][(wn * 64 + nt * 16 + la) * 32 + kc]);
#pragma unroll
        for (int mt = 0; mt < 2; ++mt)
#pragma unroll
            for (int nt = 0; nt < 4; ++nt)
                acc[mt][nt] = __builtin_amdgcn_mfma_f32_16x16x32_f16(
                    af[mt], bf[nt], acc[mt][nt], 0, 0, 0);
    };

    stage(0, 0);
    __syncthreads();
    for (int k0 = 0; k0 < K; k0 += 64) {
        stage(1, k0 + 32);
        compute(0);
        __syncthreads();
        if (k0 + 64 < K) stage(0, k0 + 64);
        compute(1);
        __syncthreads();
    }

    const int quad = lane >> 4;
    const int jb = (n0 >> 2) + wn * 16 + la;
    float bs[4];
#pragma unroll
    for (int q = 0; q < 4; ++q) bs[q] = bsum[q * 1024 + jb];
#pragma unroll
    for (int mt = 0; mt < 2; ++mt) {
#pragma unroll
        for (int r = 0; r < 4; ++r) {
            int b = m0 + wm * 32 + mt * 16 + quad * 4 + r;
            int tok = text[b * SS + step];
            const float* orow = onehT + (size_t)tok * 4096;
            float ig = acc[mt][0][r] + bs[0] + orow[jb];
            float fg = acc[mt][1][r] + bs[1] + orow[1024 + jb];
            float gg = acc[mt][2][r] + bs[2] + orow[2048 + jb];
            float og = acc[mt][3][r] + bs[3] + orow[3072 + jb];
            size_t ci = (size_t)b * 1024 + jb;
            float cn = sigmoid_fast(fg) * c[ci] + sigmoid_fast(ig) * tanh_fast(gg);
            float hn = sigmoid_fast(og) * tanh_fast(cn);
            c[ci] = cn;
            _Float16 h16 = (_Float16)hn;
            acat[(size_t)b * 2048 + 1024 + jb] = h16;
            hid[((size_t)step * BB + b) * HH + jb] = h16;
        }
    }
}

// ---------------------------------------------------------------------------
// Fused Bahdanau attention. 512 threads (8 waves) per batch row.
// Phase A: wave wv -> 16 t-rows. Phase C: split over two half-blocks.
// ---------------------------------------------------------------------------
__global__ __launch_bounds__(512) void attn_kernel(
    const _Float16* __restrict__ pH,   // [B,T,H]
    const _Float16* __restrict__ bh,   // [B,T,D]
    const float* __restrict__ ph,      // [B,H]
    const float* __restrict__ sw,      // [H]
    _Float16* __restrict__ acat) {     // [B,2048]
    __shared__ float e_s[TT];
    __shared__ float al_s[TT];
    __shared__ __align__(16) float pc[2][DD];

    const int b = blockIdx.x;
    const int tid = threadIdx.x;
    const int lane = tid & 63;
    const int wv = tid >> 6;

    // register cache of ph and sw for this lane's 16 h's
    float phr[16], swr[16];
    const float4* ph4 = (const float4*)(ph + (size_t)b * HH + lane * 16);
    const float4* sw4 = (const float4*)(sw + lane * 16);
#pragma unroll
    for (int q = 0; q < 4; ++q) {
        float4 t1 = ph4[q];
        phr[q * 4 + 0] = t1.x; phr[q * 4 + 1] = t1.y;
        phr[q * 4 + 2] = t1.z; phr[q * 4 + 3] = t1.w;
        float4 t2 = sw4[q];
        swr[q * 4 + 0] = t2.x; swr[q * 4 + 1] = t2.y;
        swr[q * 4 + 2] = t2.z; swr[q * 4 + 3] = t2.w;
    }

    // Phase A: wave wv handles t = wv*16 .. wv*16+15
    const _Float16* pHb = pH + (size_t)b * TT * HH + lane * 16;
#pragma unroll 2
    for (int tt = 0; tt < 16; ++tt) {
        int t = wv * 16 + tt;
        half8 p0 = *(const half8*)(pHb + (size_t)t * HH);
        half8 p1 = *(const half8*)(pHb + (size_t)t * HH + 8);
        float acc = 0.f;
#pragma unroll
        for (int k = 0; k < 8; ++k)
            acc += tanh_fast((float)p0[k] + phr[k]) * swr[k];
#pragma unroll
        for (int k = 0; k < 8; ++k)
            acc += tanh_fast((float)p1[k] + phr[8 + k]) * swr[8 + k];
#pragma unroll
        for (int off = 32; off > 0; off >>= 1) acc += __shfl_xor(acc, off, 64);
        if (lane == 0) e_s[t] = acc;
    }
    __syncthreads();

    // Phase B: softmax over 128 scores
    if (tid < TT) {
        float m = -1e30f;
        for (int t = 0; t < TT; ++t) m = fmaxf(m, e_s[t]);
        float s = 0.f;
        for (int t = 0; t < TT; ++t) s += __expf(e_s[t] - m);
        al_s[tid] = __expf(e_s[tid] - m) / s;
    }
    __syncthreads();

    // Phase C: half-block w2 sums t in [w2*64, w2*64+64); thread owns 4 cols
    const int w2 = tid >> 8;
    const int lc = tid & 255;
    const _Float16* bhb = bh + (size_t)b * TT * DD + lc * 4;
    float c0 = 0.f, c1 = 0.f, c2 = 0.f, c3 = 0.f;
#pragma unroll 8
    for (int t = w2 * 64; t < w2 * 64 + 64; ++t) {
        float a = al_s[t];
        half4 v = *(const half4*)(bhb + (size_t)t * DD);
        c0 += a * (float)v[0];
        c1 += a * (float)v[1];
        c2 += a * (float)v[2];
        c3 += a * (float)v[3];
    }
    ((float4*)pc[w2])[lc] = make_float4(c0, c1, c2, c3);
    __syncthreads();

    if (tid < 256) {
        float4 x0 = ((const float4*)pc[0])[tid];
        float4 x1 = ((const float4*)pc[1])[tid];
        half4 o;
        o[0] = (_Float16)(x0.x + x1.x);
        o[1] = (_Float16)(x0.y + x1.y);
        o[2] = (_Float16)(x0.z + x1.z);
        o[3] = (_Float16)(x0.w + x1.w);
        *(half4*)(acat + (size_t)b * 2048 + tid * 4) = o;
    }
}

// ---------------------------------------------------------------------------
// host
// ---------------------------------------------------------------------------
extern "C" void kernel_launch(void* const* d_in, const int* in_sizes, int n_in,
                              void* d_out, int out_size, void* d_ws, size_t ws_size,
                              hipStream_t stream) {
    const float* batch_H = (const float*)d_in[0];
    const int*   text    = (const int*)d_in[1];
    const float* i2h_w   = (const float*)d_in[2];
    const float* h2h_w   = (const float*)d_in[3];
    const float* h2h_b   = (const float*)d_in[4];
    const float* score_w = (const float*)d_in[5];
    const float* W_ih    = (const float*)d_in[6];
    const float* W_hh    = (const float*)d_in[7];
    const float* b_ih    = (const float*)d_in[8];
    const float* b_hh    = (const float*)d_in[9];
    const float* gen_w   = (const float*)d_in[10];
    const float* gen_b   = (const float*)d_in[11];
    float* out = (float*)d_out;

    char* ws = (char*)d_ws;
    size_t off = 0;
    auto carve = [&](size_t bytes) -> void* {
        void* p = ws + off;
        off += (bytes + 255) & ~(size_t)255;
        return p;
    };
    _Float16* bh16   = (_Float16*)carve((size_t)BB * TT * DD * 2);   // 128 MiB
    _Float16* pH16   = (_Float16*)carve((size_t)BB * TT * HH * 2);   // 128 MiB
    _Float16* wi2h16 = (_Float16*)carve((size_t)HH * DD * 2);
    _Float16* wh2h16 = (_Float16*)carve((size_t)HH * HH * 2);
    _Float16* wcatp  = (_Float16*)carve((size_t)4 * HH * 2048 * 2);  // 16 MiB
    _Float16* wgen16 = (_Float16*)carve((size_t)VV * HH * 2);
    float*    onehT  = (float*)carve((size_t)VV * 4 * HH * 4);       // 4 MiB
    float*    bsum   = (float*)carve((size_t)4 * HH * 4);
    _Float16* acat   = (_Float16*)carve((size_t)BB * 2048 * 2);
    float*    ph_f   = (float*)carve((size_t)BB * HH * 4);
    float*    c_f    = (float*)carve((size_t)BB * HH * 4);
    _Float16* hid16  = (_Float16*)carve((size_t)SS * BB * HH * 2);   // 26 MiB

    const dim3 blk(256);

    cvt_f32_to_f16_v4<<<dim3(16384), blk, 0, stream>>>(batch_H, bh16, (long)BB * TT * DD / 4);
    cvt_f32_to_f16_v4<<<dim3(1024), blk, 0, stream>>>(i2h_w, wi2h16, (long)HH * DD / 4);
    cvt_f32_to_f16_v4<<<dim3(1024), blk, 0, stream>>>(h2h_w, wh2h16, (long)HH * HH / 4);
    cvt_f32_to_f16_v4<<<dim3(256), blk, 0, stream>>>(gen_w, wgen16, (long)VV * HH / 4);
    build_wcatp<<<dim3(4 * HH * 2048 / 256), blk, 0, stream>>>(W_ih, W_hh, wcatp);
    build_onehT<<<dim3(VV * 4 * HH / 256), blk, 0, stream>>>(W_ih, onehT);
    build_bsum<<<dim3(16), blk, 0, stream>>>(b_ih, b_hh, bsum);
    hipMemsetAsync(acat, 0, (size_t)BB * 2048 * 2, stream);  // h0 = 0
    hipMemsetAsync(c_f, 0, (size_t)BB * HH * 4, stream);     // c0 = 0

    // proj_H = batch_H @ i2h_w^T -> f16 [B*T, H], XCD-swizzled.
    // Split into 8 M-chunks (~30 us each) so the step-loop kernels surface in
    // rocprof's top-5 next round (diagnostic; ~+5 us total cost).
    for (int i = 0; i < 8; ++i) {
        gemm_bt<1, 1><<<dim3(HH / 128, BB * TT / 128 / 8), blk, 0, stream>>>(
            bh16 + (size_t)i * (BB * TT / 8) * DD, DD, wi2h16, DD,
            pH16 + (size_t)i * (BB * TT / 8) * HH, HH, DD, nullptr);
    }

    for (int s = 0; s < SS; ++s) {
        // proj_h = h @ h2h^T + h2h_b : [512,1024], grid (16,32) = 512 blocks
        gemm_ph<<<dim3(HH / 64, BB / 16), blk, 0, stream>>>(
            acat + 1024, 2048, wh2h16, HH, ph_f, HH, HH, h2h_b);

        attn_kernel<<<dim3(BB), dim3(512), 0, stream>>>(pH16, bh16, ph_f, score_w, acat);

        // gates GEMM + fused LSTM: [512,2048] x [4096,2048]^T, grid (32,8)
        gemm_gates<<<dim3(4 * HH / 128, BB / 64), blk, 0, stream>>>(
            acat, wcatp, bsum, onehT, text, s, c_f, acat, hid16);
    }

    // logits = hid @ gen_w^T + gen_b, remap [s,b,v] -> [b,s,v]
    gemm_bt<2, 0><<<dim3(VV / 128, SS * BB / 128), blk, 0, stream>>>(
        hid16, HH, wgen16, HH, out, VV, HH, gen_b);
}

// Round 3
// 3296.692 us; speedup vs baseline: 1.0939x; 1.0939x over previous
//
#include <hip/hip_runtime.h>
#include <hip/hip_fp16.h>

// ---------------------------------------------------------------------------
// Problem constants
// ---------------------------------------------------------------------------
#define BB 512
#define TT 128
#define DD 1024
#define HH 1024
#define VV 256
#define SS 26

typedef _Float16 half8 __attribute__((ext_vector_type(8)));
typedef _Float16 half4 __attribute__((ext_vector_type(4)));
typedef float f32x4 __attribute__((ext_vector_type(4)));

// ---------------------------------------------------------------------------
// async global -> LDS, 16 B per lane. LDS dest must be wave-uniform base +
// lane*16 (it is: all our staging layouts are linear in tid).
// ---------------------------------------------------------------------------
__device__ __forceinline__ void cp16(const void* g, void* l) {
    __builtin_amdgcn_global_load_lds(
        (const __attribute__((address_space(1))) void*)g,
        (__attribute__((address_space(3))) void*)l, 16, 0, 0);
}

// ---------------------------------------------------------------------------
// fast device math
// ---------------------------------------------------------------------------
__device__ __forceinline__ float tanh_fast(float x) {
    float ex = __expf(2.f * x);
    return 1.f - 2.f * __builtin_amdgcn_rcpf(ex + 1.f);
}
__device__ __forceinline__ float sigmoid_fast(float x) {
    return __builtin_amdgcn_rcpf(1.f + __expf(-x));
}

// ---------------------------------------------------------------------------
// f32 -> f16 conversion, 4 elements/thread
// ---------------------------------------------------------------------------
__global__ void cvt_f32_to_f16_v4(const float* __restrict__ src,
                                  _Float16* __restrict__ dst, long n4) {
    long i = (long)blockIdx.x * blockDim.x + threadIdx.x;
    long stride = (long)gridDim.x * blockDim.x;
    for (; i < n4; i += stride) {
        float4 v = ((const float4*)src)[i];
        half4 h;
        h[0] = (_Float16)v.x; h[1] = (_Float16)v.y;
        h[2] = (_Float16)v.z; h[3] = (_Float16)v.w;
        ((half4*)dst)[i] = h;
    }
}

// Gate-interleaved concatenated LSTM weight:
// col c: g=c>>6, q=(c>>4)&3, jl=c&15 -> orig row q*1024+g*16+jl
__global__ void build_wcatp(const float* __restrict__ W_ih,
                            const float* __restrict__ W_hh,
                            _Float16* __restrict__ wcatp) {
    int idx = blockIdx.x * 256 + threadIdx.x;
    int c = idx >> 11;
    int k = idx & 2047;
    int g = c >> 6, q = (c >> 4) & 3, jl = c & 15;
    int row = q * 1024 + g * 16 + jl;
    float v = (k < 1024) ? W_ih[(size_t)row * 1280 + k]
                         : W_hh[(size_t)row * 1024 + (k - 1024)];
    wcatp[idx] = (_Float16)v;
}

// onehT[v][g] = W_ih[g][1024+v]   (fp32, gate-major)
__global__ void build_onehT(const float* __restrict__ W_ih,
                            float* __restrict__ onehT) {
    int idx = blockIdx.x * 256 + threadIdx.x;
    int v = idx >> 12;
    int g = idx & 4095;
    onehT[idx] = W_ih[(size_t)g * 1280 + 1024 + v];
}

__global__ void build_bsum(const float* __restrict__ b_ih,
                           const float* __restrict__ b_hh,
                           float* __restrict__ bsum) {
    int i = blockIdx.x * 256 + threadIdx.x;
    bsum[i] = b_ih[i] + b_hh[i];
}

// ---------------------------------------------------------------------------
// GEMM 128x128: C[M,N] = A[M,K]*B[N,K]^T (+bias). fp16 in, f32 acc.
// Double-buffered global->LDS staging. K multiple of 64.
// MODE 1: f16 out. MODE 2: logits remap (m -> s=m/512,b=m%512) f32 out.
// SWZ 1: XCD row-grouping swizzle (gridDim.y % 8 == 0).
// ---------------------------------------------------------------------------
template <int MODE, int SWZ>
__global__ __launch_bounds__(256) void gemm_bt(
    const _Float16* __restrict__ A, int lda,
    const _Float16* __restrict__ B, int ldb,
    void* __restrict__ Cp, int ldc, int K, const float* __restrict__ bias) {
    __shared__ __align__(16) _Float16 As[2][128 * 32];
    __shared__ __align__(16) _Float16 Bs[2][128 * 32];

    int bx = blockIdx.x, by = blockIdx.y;
    if (SWZ) {
        int nx = gridDim.x;
        int bid = by * nx + bx;
        int xcd = bid & 7;
        int local = bid >> 3;
        int rows_per_xcd = gridDim.y >> 3;
        bx = local % nx;
        by = xcd * rows_per_xcd + local / nx;
    }
    const int tid  = threadIdx.x;
    const int lane = tid & 63;
    const int wid  = tid >> 6;
    const int wm   = wid >> 1;
    const int wn   = wid & 1;
    const int m0 = by * 128;
    const int n0 = bx * 128;

    f32x4 acc[4][4];
#pragma unroll
    for (int i = 0; i < 4; ++i)
#pragma unroll
        for (int j = 0; j < 4; ++j)
            acc[i][j] = (f32x4){0.f, 0.f, 0.f, 0.f};

    const int row0 = tid >> 2;
    const int ch0  = tid & 3;
    const _Float16* a0 = A + (size_t)(m0 + row0) * lda + ch0 * 8;
    const _Float16* a1 = A + (size_t)(m0 + row0 + 64) * lda + ch0 * 8;
    const _Float16* b0 = B + (size_t)(n0 + row0) * ldb + ch0 * 8;
    const _Float16* b1 = B + (size_t)(n0 + row0 + 64) * ldb + ch0 * 8;

    const int la = lane & 15;
    const int kc = (lane >> 4) * 8;

    auto stage = [&](int buf, int k0) {
        cp16(a0 + k0, &As[buf][tid * 8]);
        cp16(a1 + k0, &As[buf][64 * 32 + tid * 8]);
        cp16(b0 + k0, &Bs[buf][tid * 8]);
        cp16(b1 + k0, &Bs[buf][64 * 32 + tid * 8]);
    };
    auto compute = [&](int buf) {
        half8 af[4], bf[4];
#pragma unroll
        for (int mt = 0; mt < 4; ++mt)
            af[mt] = *(const half8*)(&As[buf][(wm * 64 + mt * 16 + la) * 32 + kc]);
#pragma unroll
        for (int nt = 0; nt < 4; ++nt)
            bf[nt] = *(const half8*)(&Bs[buf][(wn * 64 + nt * 16 + la) * 32 + kc]);
#pragma unroll
        for (int mt = 0; mt < 4; ++mt)
#pragma unroll
            for (int nt = 0; nt < 4; ++nt)
                acc[mt][nt] = __builtin_amdgcn_mfma_f32_16x16x32_f16(
                    af[mt], bf[nt], acc[mt][nt], 0, 0, 0);
    };

    stage(0, 0);
    __syncthreads();                     // buf0 ready
    for (int k0 = 0; k0 < K; k0 += 64) {
        stage(1, k0 + 32);               // k0+32 <= K-32, always valid
        compute(0);
        __syncthreads();                 // drains stage(1); buf0 reads done
        if (k0 + 64 < K) stage(0, k0 + 64);
        compute(1);
        __syncthreads();
    }

#pragma unroll
    for (int mt = 0; mt < 4; ++mt) {
#pragma unroll
        for (int nt = 0; nt < 4; ++nt) {
            int gn = n0 + wn * 64 + nt * 16 + la;
            float bv = bias ? bias[gn] : 0.f;
#pragma unroll
            for (int r = 0; r < 4; ++r) {
                int gm = m0 + wm * 64 + mt * 16 + (lane >> 4) * 4 + r;
                float v = acc[mt][nt][r] + bv;
                if (MODE == 1) {
                    ((_Float16*)Cp)[(size_t)gm * ldc + gn] = (_Float16)v;
                } else {
                    int s = gm >> 9;
                    int b = gm & 511;
                    ((float*)Cp)[((size_t)b * SS + s) * VV + gn] = v;
                }
            }
        }
    }
}

// ---------------------------------------------------------------------------
// proj_h = h @ h2h^T + b : tile 16(M) x 64(N), grid (16,32) = 512 blocks
// (2 blocks/CU so barrier drains overlap across blocks). dbuf prefetch loop.
// 4 waves, wave w owns cols w*16..w*16+15 -> one 16x16x32 MFMA per K-step.
// ---------------------------------------------------------------------------
__global__ __launch_bounds__(256) void gemm_ph(
    const _Float16* __restrict__ A, int lda,
    const _Float16* __restrict__ B, int ldb,
    float* __restrict__ C, int ldc, int K, const float* __restrict__ bias) {
    __shared__ __align__(16) _Float16 As[2][16 * 32];
    __shared__ __align__(16) _Float16 Bs[2][64 * 32];
    const int tid  = threadIdx.x;
    const int lane = tid & 63;
    const int wid  = tid >> 6;
    const int m0 = blockIdx.y * 16;
    const int n0 = blockIdx.x * 64;
    const int row = tid >> 2;
    const int ch  = tid & 3;
    const _Float16* ag = A + (size_t)(m0 + (row & 15)) * lda + ch * 8;
    const _Float16* bg = B + (size_t)(n0 + row) * ldb + ch * 8;
    f32x4 acc = (f32x4){0.f, 0.f, 0.f, 0.f};
    const int la = lane & 15;
    const int kc = (lane >> 4) * 8;

    auto stage = [&](int buf, int k0) {
        if (tid < 64) cp16(ag + k0, &As[buf][tid * 8]);
        cp16(bg + k0, &Bs[buf][tid * 8]);
    };
    auto compute = [&](int buf) {
        half8 af = *(const half8*)(&As[buf][la * 32 + kc]);
        half8 bf = *(const half8*)(&Bs[buf][(wid * 16 + la) * 32 + kc]);
        acc = __builtin_amdgcn_mfma_f32_16x16x32_f16(af, bf, acc, 0, 0, 0);
    };

    stage(0, 0);
    __syncthreads();
    for (int k0 = 0; k0 < K; k0 += 64) {
        stage(1, k0 + 32);
        compute(0);
        __syncthreads();
        if (k0 + 64 < K) stage(0, k0 + 64);
        compute(1);
        __syncthreads();
    }

    int gn = n0 + wid * 16 + la;
    float bv = bias[gn];
    int gm0 = m0 + (lane >> 4) * 4;
#pragma unroll
    for (int r = 0; r < 4; ++r)
        C[(size_t)(gm0 + r) * ldc + gn] = acc[r] + bv;
}

// ---------------------------------------------------------------------------
// gates GEMM over gate-interleaved wcatp + fused LSTM pointwise epilogue.
// Tile 64x64, grid (64,8) = 512 blocks = 2 blocks/CU (cross-block overlap of
// barrier drains, m114). Wave wid owns rows wid*16..+15 x all 64 cols, so
// each wave still spans one full gate-group (nt == gate index q).
// ---------------------------------------------------------------------------
__global__ __launch_bounds__(256) void gemm_gates(
    const _Float16* __restrict__ A,      // acat [B,2048]
    const _Float16* __restrict__ B,      // wcatp [4096,2048]
    const float* __restrict__ bsum,      // [4096] gate-major
    const float* __restrict__ onehT,     // [V,4096] gate-major
    const int* __restrict__ text,        // [B,SS]
    int step,
    float* __restrict__ c,               // [B,H]
    _Float16* __restrict__ acat,         // [B,2048] (h -> cols 1024:2048)
    _Float16* __restrict__ hid) {        // [SS,B,H]
    __shared__ __align__(16) _Float16 As[2][64 * 32];
    __shared__ __align__(16) _Float16 Bs[2][64 * 32];
    const int tid  = threadIdx.x;
    const int lane = tid & 63;
    const int wid  = tid >> 6;
    const int m0 = blockIdx.y * 64;
    const int n0 = blockIdx.x * 64;
    const int K  = 2048;

    f32x4 acc[4];
#pragma unroll
    for (int j = 0; j < 4; ++j) acc[j] = (f32x4){0.f, 0.f, 0.f, 0.f};

    const int row0 = tid >> 2;
    const int ch0  = tid & 3;
    const _Float16* ag = A + (size_t)(m0 + row0) * 2048 + ch0 * 8;
    const _Float16* bg = B + (size_t)(n0 + row0) * 2048 + ch0 * 8;
    const int la = lane & 15;
    const int kc = (lane >> 4) * 8;

    auto stage = [&](int buf, int k0) {
        cp16(ag + k0, &As[buf][tid * 8]);
        cp16(bg + k0, &Bs[buf][tid * 8]);
    };
    auto compute = [&](int buf) {
        half8 af = *(const half8*)(&As[buf][(wid * 16 + la) * 32 + kc]);
        half8 bf[4];
#pragma unroll
        for (int nt = 0; nt < 4; ++nt)
            bf[nt] = *(const half8*)(&Bs[buf][(nt * 16 + la) * 32 + kc]);
#pragma unroll
        for (int nt = 0; nt < 4; ++nt)
            acc[nt] = __builtin_amdgcn_mfma_f32_16x16x32_f16(
                af, bf[nt], acc[nt], 0, 0, 0);
    };

    stage(0, 0);
    __syncthreads();
    for (int k0 = 0; k0 < K; k0 += 64) {
        stage(1, k0 + 32);
        compute(0);
        __syncthreads();
        if (k0 + 64 < K) stage(0, k0 + 64);
        compute(1);
        __syncthreads();
    }

    const int quad = lane >> 4;
    const int jb = (n0 >> 2) + la;       // h-index: (n0>>6)*16 + la
    float bs[4];
#pragma unroll
    for (int q = 0; q < 4; ++q) bs[q] = bsum[q * 1024 + jb];
#pragma unroll
    for (int r = 0; r < 4; ++r) {
        int b = m0 + wid * 16 + quad * 4 + r;
        int tok = text[b * SS + step];
        const float* orow = onehT + (size_t)tok * 4096;
        float ig = acc[0][r] + bs[0] + orow[jb];
        float fg = acc[1][r] + bs[1] + orow[1024 + jb];
        float gg = acc[2][r] + bs[2] + orow[2048 + jb];
        float og = acc[3][r] + bs[3] + orow[3072 + jb];
        size_t ci = (size_t)b * 1024 + jb;
        float cn = sigmoid_fast(fg) * c[ci] + sigmoid_fast(ig) * tanh_fast(gg);
        float hn = sigmoid_fast(og) * tanh_fast(cn);
        c[ci] = cn;
        _Float16 h16 = (_Float16)hn;
        acat[(size_t)b * 2048 + 1024 + jb] = h16;
        hid[((size_t)step * BB + b) * HH + jb] = h16;
    }
}

// ---------------------------------------------------------------------------
// Fused Bahdanau attention. 512 threads (8 waves) per batch row.
// Phase A: wave wv -> 16 t-rows (16B/lane half8 loads).
// Phase B: wave-0 shuffle-reduce softmax.
// Phase C: 4-way t-split, 16B/lane half8 loads, conflict-free LDS partials.
// ---------------------------------------------------------------------------
__global__ __launch_bounds__(512) void attn_kernel(
    const _Float16* __restrict__ pH,   // [B,T,H]
    const _Float16* __restrict__ bh,   // [B,T,D]
    const float* __restrict__ ph,      // [B,H]
    const float* __restrict__ sw,      // [H]
    _Float16* __restrict__ acat) {     // [B,2048]
    __shared__ float e_s[TT];
    __shared__ float al_s[TT];
    __shared__ __align__(16) float4 pc2[4][2][128];  // 16 KB partials

    const int b = blockIdx.x;
    const int tid = threadIdx.x;
    const int lane = tid & 63;
    const int wv = tid >> 6;

    // register cache of ph and sw for this lane's 16 h's
    float phr[16], swr[16];
    const float4* ph4 = (const float4*)(ph + (size_t)b * HH + lane * 16);
    const float4* sw4 = (const float4*)(sw + lane * 16);
#pragma unroll
    for (int q = 0; q < 4; ++q) {
        float4 t1 = ph4[q];
        phr[q * 4 + 0] = t1.x; phr[q * 4 + 1] = t1.y;
        phr[q * 4 + 2] = t1.z; phr[q * 4 + 3] = t1.w;
        float4 t2 = sw4[q];
        swr[q * 4 + 0] = t2.x; swr[q * 4 + 1] = t2.y;
        swr[q * 4 + 2] = t2.z; swr[q * 4 + 3] = t2.w;
    }

    // Phase A: wave wv handles t = wv*16 .. wv*16+15
    const _Float16* pHb = pH + (size_t)b * TT * HH + lane * 16;
#pragma unroll 2
    for (int tt = 0; tt < 16; ++tt) {
        int t = wv * 16 + tt;
        half8 p0 = *(const half8*)(pHb + (size_t)t * HH);
        half8 p1 = *(const half8*)(pHb + (size_t)t * HH + 8);
        float acc = 0.f;
#pragma unroll
        for (int k = 0; k < 8; ++k)
            acc += tanh_fast((float)p0[k] + phr[k]) * swr[k];
#pragma unroll
        for (int k = 0; k < 8; ++k)
            acc += tanh_fast((float)p1[k] + phr[8 + k]) * swr[8 + k];
#pragma unroll
        for (int off = 32; off > 0; off >>= 1) acc += __shfl_xor(acc, off, 64);
        if (lane == 0) e_s[t] = acc;
    }
    __syncthreads();

    // Phase B: wave-0 parallel softmax over 128 scores
    if (tid < 64) {
        float e0 = e_s[tid];
        float e1 = e_s[64 + tid];
        float m = fmaxf(e0, e1);
#pragma unroll
        for (int off = 32; off > 0; off >>= 1)
            m = fmaxf(m, __shfl_xor(m, off, 64));
        float x0 = __expf(e0 - m);
        float x1 = __expf(e1 - m);
        float ssum = x0 + x1;
#pragma unroll
        for (int off = 32; off > 0; off >>= 1)
            ssum += __shfl_xor(ssum, off, 64);
        float inv = __builtin_amdgcn_rcpf(ssum);
        al_s[tid] = x0 * inv;
        al_s[64 + tid] = x1 * inv;
    }
    __syncthreads();

    // Phase C: quarter-group w4 sums t in [w4*32, w4*32+32); thread owns 8
    // cols (one half8 = 16B load per t). Partials in tid-contiguous float4
    // slots (conflict-free b128 pattern).
    const int w4 = tid >> 7;
    const int lc = tid & 127;
    const _Float16* bhb = bh + (size_t)b * TT * DD + lc * 8;
    float c0 = 0.f, c1 = 0.f, c2 = 0.f, c3 = 0.f;
    float c4 = 0.f, c5 = 0.f, c6 = 0.f, c7 = 0.f;
#pragma unroll 4
    for (int t = w4 * 32; t < w4 * 32 + 32; ++t) {
        float a = al_s[t];
        half8 v = *(const half8*)(bhb + (size_t)t * DD);
        c0 += a * (float)v[0];
        c1 += a * (float)v[1];
        c2 += a * (float)v[2];
        c3 += a * (float)v[3];
        c4 += a * (float)v[4];
        c5 += a * (float)v[5];
        c6 += a * (float)v[6];
        c7 += a * (float)v[7];
    }
    pc2[w4][0][lc] = make_float4(c0, c1, c2, c3);
    pc2[w4][1][lc] = make_float4(c4, c5, c6, c7);
    __syncthreads();

    // reduce 4 partials; thread t writes cols t*4..t*4+3
    if (tid < 256) {
        int hf = tid & 1, slot = tid >> 1;
        float4 s0 = pc2[0][hf][slot];
        float4 s1 = pc2[1][hf][slot];
        float4 s2 = pc2[2][hf][slot];
        float4 s3 = pc2[3][hf][slot];
        half4 o;
        o[0] = (_Float16)(s0.x + s1.x + s2.x + s3.x);
        o[1] = (_Float16)(s0.y + s1.y + s2.y + s3.y);
        o[2] = (_Float16)(s0.z + s1.z + s2.z + s3.z);
        o[3] = (_Float16)(s0.w + s1.w + s2.w + s3.w);
        *(half4*)(acat + (size_t)b * 2048 + tid * 4) = o;
    }
}

// ---------------------------------------------------------------------------
// host
// ---------------------------------------------------------------------------
extern "C" void kernel_launch(void* const* d_in, const int* in_sizes, int n_in,
                              void* d_out, int out_size, void* d_ws, size_t ws_size,
                              hipStream_t stream) {
    const float* batch_H = (const float*)d_in[0];
    const int*   text    = (const int*)d_in[1];
    const float* i2h_w   = (const float*)d_in[2];
    const float* h2h_w   = (const float*)d_in[3];
    const float* h2h_b   = (const float*)d_in[4];
    const float* score_w = (const float*)d_in[5];
    const float* W_ih    = (const float*)d_in[6];
    const float* W_hh    = (const float*)d_in[7];
    const float* b_ih    = (const float*)d_in[8];
    const float* b_hh    = (const float*)d_in[9];
    const float* gen_w   = (const float*)d_in[10];
    const float* gen_b   = (const float*)d_in[11];
    float* out = (float*)d_out;

    char* ws = (char*)d_ws;
    size_t off = 0;
    auto carve = [&](size_t bytes) -> void* {
        void* p = ws + off;
        off += (bytes + 255) & ~(size_t)255;
        return p;
    };
    _Float16* bh16   = (_Float16*)carve((size_t)BB * TT * DD * 2);   // 128 MiB
    _Float16* pH16   = (_Float16*)carve((size_t)BB * TT * HH * 2);   // 128 MiB
    _Float16* wi2h16 = (_Float16*)carve((size_t)HH * DD * 2);
    _Float16* wh2h16 = (_Float16*)carve((size_t)HH * HH * 2);
    _Float16* wcatp  = (_Float16*)carve((size_t)4 * HH * 2048 * 2);  // 16 MiB
    _Float16* wgen16 = (_Float16*)carve((size_t)VV * HH * 2);
    float*    onehT  = (float*)carve((size_t)VV * 4 * HH * 4);       // 4 MiB
    float*    bsum   = (float*)carve((size_t)4 * HH * 4);
    _Float16* acat   = (_Float16*)carve((size_t)BB * 2048 * 2);
    float*    ph_f   = (float*)carve((size_t)BB * HH * 4);
    float*    c_f    = (float*)carve((size_t)BB * HH * 4);
    _Float16* hid16  = (_Float16*)carve((size_t)SS * BB * HH * 2);   // 26 MiB

    const dim3 blk(256);

    cvt_f32_to_f16_v4<<<dim3(16384), blk, 0, stream>>>(batch_H, bh16, (long)BB * TT * DD / 4);
    cvt_f32_to_f16_v4<<<dim3(1024), blk, 0, stream>>>(i2h_w, wi2h16, (long)HH * DD / 4);
    cvt_f32_to_f16_v4<<<dim3(1024), blk, 0, stream>>>(h2h_w, wh2h16, (long)HH * HH / 4);
    cvt_f32_to_f16_v4<<<dim3(256), blk, 0, stream>>>(gen_w, wgen16, (long)VV * HH / 4);
    build_wcatp<<<dim3(4 * HH * 2048 / 256), blk, 0, stream>>>(W_ih, W_hh, wcatp);
    build_onehT<<<dim3(VV * 4 * HH / 256), blk, 0, stream>>>(W_ih, onehT);
    build_bsum<<<dim3(16), blk, 0, stream>>>(b_ih, b_hh, bsum);
    hipMemsetAsync(acat, 0, (size_t)BB * 2048 * 2, stream);  // h0 = 0
    hipMemsetAsync(c_f, 0, (size_t)BB * HH * 4, stream);     // c0 = 0

    // proj_H = batch_H @ i2h_w^T -> f16 [B*T, H], XCD-swizzled
    gemm_bt<1, 1><<<dim3(HH / 128, BB * TT / 128), blk, 0, stream>>>(
        bh16, DD, wi2h16, DD, pH16, HH, DD, nullptr);

    for (int s = 0; s < SS; ++s) {
        // proj_h = h @ h2h^T + h2h_b : [512,1024], grid (16,32) = 512 blocks
        gemm_ph<<<dim3(HH / 64, BB / 16), blk, 0, stream>>>(
            acat + 1024, 2048, wh2h16, HH, ph_f, HH, HH, h2h_b);

        attn_kernel<<<dim3(BB), dim3(512), 0, stream>>>(pH16, bh16, ph_f, score_w, acat);

        // gates GEMM + fused LSTM: [512,2048] x [4096,2048]^T, grid (64,8)
        gemm_gates<<<dim3(4 * HH / 64, BB / 64), blk, 0, stream>>>(
            acat, wcatp, bsum, onehT, text, s, c_f, acat, hid16);
    }

    // logits = hid @ gen_w^T + gen_b, remap [s,b,v] -> [b,s,v]
    gemm_bt<2, 0><<<dim3(VV / 128, SS * BB / 128), blk, 0, stream>>>(
        hid16, HH, wgen16, HH, out, VV, HH, gen_b);
}

// Round 4
// 3291.305 us; speedup vs baseline: 1.0957x; 1.0016x over previous
//
#include <hip/hip_runtime.h>
#include <hip/hip_fp16.h>

// ---------------------------------------------------------------------------
// Problem constants
// ---------------------------------------------------------------------------
#define BB 512
#define TT 128
#define DD 1024
#define HH 1024
#define VV 256
#define SS 26

typedef _Float16 half8 __attribute__((ext_vector_type(8)));
typedef _Float16 half4 __attribute__((ext_vector_type(4)));
typedef float f32x4 __attribute__((ext_vector_type(4)));

// ---------------------------------------------------------------------------
// async global -> LDS, 16 B per lane. LDS dest must be wave-uniform base +
// lane*16 (it is: all our staging layouts are linear in tid).
// ---------------------------------------------------------------------------
__device__ __forceinline__ void cp16(const void* g, void* l) {
    __builtin_amdgcn_global_load_lds(
        (const __attribute__((address_space(1))) void*)g,
        (__attribute__((address_space(3))) void*)l, 16, 0, 0);
}

// ---------------------------------------------------------------------------
// fast device math
// ---------------------------------------------------------------------------
__device__ __forceinline__ float tanh_fast(float x) {
    float ex = __expf(2.f * x);
    return 1.f - 2.f * __builtin_amdgcn_rcpf(ex + 1.f);
}
__device__ __forceinline__ float sigmoid_fast(float x) {
    return __builtin_amdgcn_rcpf(1.f + __expf(-x));
}

// ---------------------------------------------------------------------------
// f32 -> f16 conversion, 4 elements/thread
// ---------------------------------------------------------------------------
__global__ void cvt_f32_to_f16_v4(const float* __restrict__ src,
                                  _Float16* __restrict__ dst, long n4) {
    long i = (long)blockIdx.x * blockDim.x + threadIdx.x;
    long stride = (long)gridDim.x * blockDim.x;
    for (; i < n4; i += stride) {
        float4 v = ((const float4*)src)[i];
        half4 h;
        h[0] = (_Float16)v.x; h[1] = (_Float16)v.y;
        h[2] = (_Float16)v.z; h[3] = (_Float16)v.w;
        ((half4*)dst)[i] = h;
    }
}

// Gate-interleaved concatenated LSTM weight:
// col c: g=c>>6, q=(c>>4)&3, jl=c&15 -> orig row q*1024+g*16+jl
__global__ void build_wcatp(const float* __restrict__ W_ih,
                            const float* __restrict__ W_hh,
                            _Float16* __restrict__ wcatp) {
    int idx = blockIdx.x * 256 + threadIdx.x;
    int c = idx >> 11;
    int k = idx & 2047;
    int g = c >> 6, q = (c >> 4) & 3, jl = c & 15;
    int row = q * 1024 + g * 16 + jl;
    float v = (k < 1024) ? W_ih[(size_t)row * 1280 + k]
                         : W_hh[(size_t)row * 1024 + (k - 1024)];
    wcatp[idx] = (_Float16)v;
}

// onehT[v][g] = W_ih[g][1024+v]   (fp32, gate-major)
__global__ void build_onehT(const float* __restrict__ W_ih,
                            float* __restrict__ onehT) {
    int idx = blockIdx.x * 256 + threadIdx.x;
    int v = idx >> 12;
    int g = idx & 4095;
    onehT[idx] = W_ih[(size_t)g * 1280 + 1024 + v];
}

__global__ void build_bsum(const float* __restrict__ b_ih,
                           const float* __restrict__ b_hh,
                           float* __restrict__ bsum) {
    int i = blockIdx.x * 256 + threadIdx.x;
    bsum[i] = b_ih[i] + b_hh[i];
}

// ---------------------------------------------------------------------------
// GEMM 128x128: C[M,N] = A[M,K]*B[N,K]^T (+bias). fp16 in, f32 acc.
// Double-buffered global->LDS staging. K multiple of 64.
// MODE 1: f16 out. MODE 2: logits remap (m -> s=m/512,b=m%512) f32 out.
// SWZ 1: XCD row-grouping swizzle (gridDim.y % 8 == 0).
// ---------------------------------------------------------------------------
template <int MODE, int SWZ>
__global__ __launch_bounds__(256) void gemm_bt(
    const _Float16* __restrict__ A, int lda,
    const _Float16* __restrict__ B, int ldb,
    void* __restrict__ Cp, int ldc, int K, const float* __restrict__ bias) {
    __shared__ __align__(16) _Float16 As[2][128 * 32];
    __shared__ __align__(16) _Float16 Bs[2][128 * 32];

    int bx = blockIdx.x, by = blockIdx.y;
    if (SWZ) {
        int nx = gridDim.x;
        int bid = by * nx + bx;
        int xcd = bid & 7;
        int local = bid >> 3;
        int rows_per_xcd = gridDim.y >> 3;
        bx = local % nx;
        by = xcd * rows_per_xcd + local / nx;
    }
    const int tid  = threadIdx.x;
    const int lane = tid & 63;
    const int wid  = tid >> 6;
    const int wm   = wid >> 1;
    const int wn   = wid & 1;
    const int m0 = by * 128;
    const int n0 = bx * 128;

    f32x4 acc[4][4];
#pragma unroll
    for (int i = 0; i < 4; ++i)
#pragma unroll
        for (int j = 0; j < 4; ++j)
            acc[i][j] = (f32x4){0.f, 0.f, 0.f, 0.f};

    const int row0 = tid >> 2;
    const int ch0  = tid & 3;
    const _Float16* a0 = A + (size_t)(m0 + row0) * lda + ch0 * 8;
    const _Float16* a1 = A + (size_t)(m0 + row0 + 64) * lda + ch0 * 8;
    const _Float16* b0 = B + (size_t)(n0 + row0) * ldb + ch0 * 8;
    const _Float16* b1 = B + (size_t)(n0 + row0 + 64) * ldb + ch0 * 8;

    const int la = lane & 15;
    const int kc = (lane >> 4) * 8;

    auto stage = [&](int buf, int k0) {
        cp16(a0 + k0, &As[buf][tid * 8]);
        cp16(a1 + k0, &As[buf][64 * 32 + tid * 8]);
        cp16(b0 + k0, &Bs[buf][tid * 8]);
        cp16(b1 + k0, &Bs[buf][64 * 32 + tid * 8]);
    };
    auto compute = [&](int buf) {
        half8 af[4], bf[4];
#pragma unroll
        for (int mt = 0; mt < 4; ++mt)
            af[mt] = *(const half8*)(&As[buf][(wm * 64 + mt * 16 + la) * 32 + kc]);
#pragma unroll
        for (int nt = 0; nt < 4; ++nt)
            bf[nt] = *(const half8*)(&Bs[buf][(wn * 64 + nt * 16 + la) * 32 + kc]);
#pragma unroll
        for (int mt = 0; mt < 4; ++mt)
#pragma unroll
            for (int nt = 0; nt < 4; ++nt)
                acc[mt][nt] = __builtin_amdgcn_mfma_f32_16x16x32_f16(
                    af[mt], bf[nt], acc[mt][nt], 0, 0, 0);
    };

    stage(0, 0);
    __syncthreads();                     // buf0 ready
    for (int k0 = 0; k0 < K; k0 += 64) {
        stage(1, k0 + 32);               // k0+32 <= K-32, always valid
        compute(0);
        __syncthreads();                 // drains stage(1); buf0 reads done
        if (k0 + 64 < K) stage(0, k0 + 64);
        compute(1);
        __syncthreads();
    }

#pragma unroll
    for (int mt = 0; mt < 4; ++mt) {
#pragma unroll
        for (int nt = 0; nt < 4; ++nt) {
            int gn = n0 + wn * 64 + nt * 16 + la;
            float bv = bias ? bias[gn] : 0.f;
#pragma unroll
            for (int r = 0; r < 4; ++r) {
                int gm = m0 + wm * 64 + mt * 16 + (lane >> 4) * 4 + r;
                float v = acc[mt][nt][r] + bv;
                if (MODE == 1) {
                    ((_Float16*)Cp)[(size_t)gm * ldc + gn] = (_Float16)v;
                } else {
                    int s = gm >> 9;
                    int b = gm & 511;
                    ((float*)Cp)[((size_t)b * SS + s) * VV + gn] = v;
                }
            }
        }
    }
}

// ---------------------------------------------------------------------------
// proj_h = h @ h2h^T + b : tile 16(M) x 64(N), grid (16,32) = 512 blocks
// (2 blocks/CU so barrier drains overlap across blocks). dbuf prefetch loop.
// 4 waves, wave w owns cols w*16..w*16+15 -> one 16x16x32 MFMA per K-step.
// ---------------------------------------------------------------------------
__global__ __launch_bounds__(256) void gemm_ph(
    const _Float16* __restrict__ A, int lda,
    const _Float16* __restrict__ B, int ldb,
    float* __restrict__ C, int ldc, int K, const float* __restrict__ bias) {
    __shared__ __align__(16) _Float16 As[2][16 * 32];
    __shared__ __align__(16) _Float16 Bs[2][64 * 32];
    const int tid  = threadIdx.x;
    const int lane = tid & 63;
    const int wid  = tid >> 6;
    const int m0 = blockIdx.y * 16;
    const int n0 = blockIdx.x * 64;
    const int row = tid >> 2;
    const int ch  = tid & 3;
    const _Float16* ag = A + (size_t)(m0 + (row & 15)) * lda + ch * 8;
    const _Float16* bg = B + (size_t)(n0 + row) * ldb + ch * 8;
    f32x4 acc = (f32x4){0.f, 0.f, 0.f, 0.f};
    const int la = lane & 15;
    const int kc = (lane >> 4) * 8;

    auto stage = [&](int buf, int k0) {
        if (tid < 64) cp16(ag + k0, &As[buf][tid * 8]);
        cp16(bg + k0, &Bs[buf][tid * 8]);
    };
    auto compute = [&](int buf) {
        half8 af = *(const half8*)(&As[buf][la * 32 + kc]);
        half8 bf = *(const half8*)(&Bs[buf][(wid * 16 + la) * 32 + kc]);
        acc = __builtin_amdgcn_mfma_f32_16x16x32_f16(af, bf, acc, 0, 0, 0);
    };

    stage(0, 0);
    __syncthreads();
    for (int k0 = 0; k0 < K; k0 += 64) {
        stage(1, k0 + 32);
        compute(0);
        __syncthreads();
        if (k0 + 64 < K) stage(0, k0 + 64);
        compute(1);
        __syncthreads();
    }

    int gn = n0 + wid * 16 + la;
    float bv = bias[gn];
    int gm0 = m0 + (lane >> 4) * 4;
#pragma unroll
    for (int r = 0; r < 4; ++r)
        C[(size_t)(gm0 + r) * ldc + gn] = acc[r] + bv;
}

// ---------------------------------------------------------------------------
// gates GEMM over gate-interleaved wcatp + fused LSTM pointwise epilogue.
// Tile 64x64, grid (64,8) = 512 blocks = 2 blocks/CU (cross-block overlap of
// barrier drains, m114). Wave wid owns rows wid*16..+15 x all 64 cols, so
// each wave still spans one full gate-group (nt == gate index q).
// ---------------------------------------------------------------------------
__global__ __launch_bounds__(256) void gemm_gates(
    const _Float16* __restrict__ A,      // acat [B,2048]
    const _Float16* __restrict__ B,      // wcatp [4096,2048]
    const float* __restrict__ bsum,      // [4096] gate-major
    const float* __restrict__ onehT,     // [V,4096] gate-major
    const int* __restrict__ text,        // [B,SS]
    int step,
    float* __restrict__ c,               // [B,H]
    _Float16* __restrict__ acat,         // [B,2048] (h -> cols 1024:2048)
    _Float16* __restrict__ hid) {        // [SS,B,H]
    __shared__ __align__(16) _Float16 As[2][64 * 32];
    __shared__ __align__(16) _Float16 Bs[2][64 * 32];
    const int tid  = threadIdx.x;
    const int lane = tid & 63;
    const int wid  = tid >> 6;
    const int m0 = blockIdx.y * 64;
    const int n0 = blockIdx.x * 64;
    const int K  = 2048;

    f32x4 acc[4];
#pragma unroll
    for (int j = 0; j < 4; ++j) acc[j] = (f32x4){0.f, 0.f, 0.f, 0.f};

    const int row0 = tid >> 2;
    const int ch0  = tid & 3;
    const _Float16* ag = A + (size_t)(m0 + row0) * 2048 + ch0 * 8;
    const _Float16* bg = B + (size_t)(n0 + row0) * 2048 + ch0 * 8;
    const int la = lane & 15;
    const int kc = (lane >> 4) * 8;

    auto stage = [&](int buf, int k0) {
        cp16(ag + k0, &As[buf][tid * 8]);
        cp16(bg + k0, &Bs[buf][tid * 8]);
    };
    auto compute = [&](int buf) {
        half8 af = *(const half8*)(&As[buf][(wid * 16 + la) * 32 + kc]);
        half8 bf[4];
#pragma unroll
        for (int nt = 0; nt < 4; ++nt)
            bf[nt] = *(const half8*)(&Bs[buf][(nt * 16 + la) * 32 + kc]);
#pragma unroll
        for (int nt = 0; nt < 4; ++nt)
            acc[nt] = __builtin_amdgcn_mfma_f32_16x16x32_f16(
                af, bf[nt], acc[nt], 0, 0, 0);
    };

    stage(0, 0);
    __syncthreads();
    for (int k0 = 0; k0 < K; k0 += 64) {
        stage(1, k0 + 32);
        compute(0);
        __syncthreads();
        if (k0 + 64 < K) stage(0, k0 + 64);
        compute(1);
        __syncthreads();
    }

    const int quad = lane >> 4;
    const int jb = (n0 >> 2) + la;       // h-index: (n0>>6)*16 + la
    float bs[4];
#pragma unroll
    for (int q = 0; q < 4; ++q) bs[q] = bsum[q * 1024 + jb];
#pragma unroll
    for (int r = 0; r < 4; ++r) {
        int b = m0 + wid * 16 + quad * 4 + r;
        int tok = text[b * SS + step];
        const float* orow = onehT + (size_t)tok * 4096;
        float ig = acc[0][r] + bs[0] + orow[jb];
        float fg = acc[1][r] + bs[1] + orow[1024 + jb];
        float gg = acc[2][r] + bs[2] + orow[2048 + jb];
        float og = acc[3][r] + bs[3] + orow[3072 + jb];
        size_t ci = (size_t)b * 1024 + jb;
        float cn = sigmoid_fast(fg) * c[ci] + sigmoid_fast(ig) * tanh_fast(gg);
        float hn = sigmoid_fast(og) * tanh_fast(cn);
        c[ci] = cn;
        _Float16 h16 = (_Float16)hn;
        acat[(size_t)b * 2048 + 1024 + jb] = h16;
        hid[((size_t)step * BB + b) * HH + jb] = h16;
    }
}

// ---------------------------------------------------------------------------
// Fused Bahdanau attention. 512 threads (8 waves) per batch row.
// Latency-bound fix (this round): explicit ping-pong software pipelines.
// Phase A: wave wv -> 16 t-rows, 4 chunks of 4 t; next chunk's 8 half8 loads
//          issued BEFORE computing the current chunk (128 B/lane in flight).
// Phase B: wave-0 shuffle-reduce softmax.
// Phase C: 4-way t-split, 4 chunks of 8 t, same ping-pong (128 B/lane).
// All math is per-t identical to the round-3 version (same absmax).
// ---------------------------------------------------------------------------
__global__ __launch_bounds__(512) void attn_kernel(
    const _Float16* __restrict__ pH,   // [B,T,H]
    const _Float16* __restrict__ bh,   // [B,T,D]
    const float* __restrict__ ph,      // [B,H]
    const float* __restrict__ sw,      // [H]
    _Float16* __restrict__ acat) {     // [B,2048]
    __shared__ float e_s[TT];
    __shared__ float al_s[TT];
    __shared__ __align__(16) float4 pc2[4][2][128];  // 16 KB partials

    const int b = blockIdx.x;
    const int tid = threadIdx.x;
    const int lane = tid & 63;
    const int wv = tid >> 6;

    // register cache of ph and sw for this lane's 16 h's
    float phr[16], swr[16];
    const float4* ph4 = (const float4*)(ph + (size_t)b * HH + lane * 16);
    const float4* sw4 = (const float4*)(sw + lane * 16);
#pragma unroll
    for (int q = 0; q < 4; ++q) {
        float4 t1 = ph4[q];
        phr[q * 4 + 0] = t1.x; phr[q * 4 + 1] = t1.y;
        phr[q * 4 + 2] = t1.z; phr[q * 4 + 3] = t1.w;
        float4 t2 = sw4[q];
        swr[q * 4 + 0] = t2.x; swr[q * 4 + 1] = t2.y;
        swr[q * 4 + 2] = t2.z; swr[q * 4 + 3] = t2.w;
    }

    // Phase A: wave wv handles t = wv*16 .. wv*16+15, pipelined in 4-t chunks
    const _Float16* pHb = pH + (size_t)b * TT * HH + lane * 16;
    {
        half8 bufA[4][2], bufB[4][2];
        auto LOADC = [&](half8 (*buf)[2], int c) {
#pragma unroll
            for (int i = 0; i < 4; ++i) {
                int t = wv * 16 + c * 4 + i;
                buf[i][0] = *(const half8*)(pHb + (size_t)t * HH);
                buf[i][1] = *(const half8*)(pHb + (size_t)t * HH + 8);
            }
        };
        auto COMPC = [&](half8 (*buf)[2], int c) {
#pragma unroll
            for (int i = 0; i < 4; ++i) {
                int t = wv * 16 + c * 4 + i;
                float acc = 0.f;
#pragma unroll
                for (int k = 0; k < 8; ++k)
                    acc += tanh_fast((float)buf[i][0][k] + phr[k]) * swr[k];
#pragma unroll
                for (int k = 0; k < 8; ++k)
                    acc += tanh_fast((float)buf[i][1][k] + phr[8 + k]) * swr[8 + k];
#pragma unroll
                for (int off = 32; off > 0; off >>= 1)
                    acc += __shfl_xor(acc, off, 64);
                if (lane == 0) e_s[t] = acc;
            }
        };
        LOADC(bufA, 0);
        LOADC(bufB, 1); COMPC(bufA, 0);
        LOADC(bufA, 2); COMPC(bufB, 1);
        LOADC(bufB, 3); COMPC(bufA, 2);
        COMPC(bufB, 3);
    }
    __syncthreads();

    // Phase B: wave-0 parallel softmax over 128 scores
    if (tid < 64) {
        float e0 = e_s[tid];
        float e1 = e_s[64 + tid];
        float m = fmaxf(e0, e1);
#pragma unroll
        for (int off = 32; off > 0; off >>= 1)
            m = fmaxf(m, __shfl_xor(m, off, 64));
        float x0 = __expf(e0 - m);
        float x1 = __expf(e1 - m);
        float ssum = x0 + x1;
#pragma unroll
        for (int off = 32; off > 0; off >>= 1)
            ssum += __shfl_xor(ssum, off, 64);
        float inv = __builtin_amdgcn_rcpf(ssum);
        al_s[tid] = x0 * inv;
        al_s[64 + tid] = x1 * inv;
    }
    __syncthreads();

    // Phase C: quarter-group w4 sums t in [w4*32, w4*32+32); thread owns 8
    // cols. Pipelined in 8-t chunks with ping-pong register rings.
    const int w4 = tid >> 7;
    const int lc = tid & 127;
    const _Float16* bhb = bh + (size_t)b * TT * DD + lc * 8;
    float c0 = 0.f, c1 = 0.f, c2 = 0.f, c3 = 0.f;
    float c4 = 0.f, c5 = 0.f, c6 = 0.f, c7 = 0.f;
    {
        half8 vA[8], vB[8];
        float aA[8], aB[8];
        auto LOADV = [&](half8* v, float* a, int c) {
#pragma unroll
            for (int i = 0; i < 8; ++i) {
                int t = w4 * 32 + c * 8 + i;
                v[i] = *(const half8*)(bhb + (size_t)t * DD);
                a[i] = al_s[t];
            }
        };
        auto COMPV = [&](const half8* v, const float* a) {
#pragma unroll
            for (int i = 0; i < 8; ++i) {
                float av = a[i];
                c0 += av * (float)v[i][0];
                c1 += av * (float)v[i][1];
                c2 += av * (float)v[i][2];
                c3 += av * (float)v[i][3];
                c4 += av * (float)v[i][4];
                c5 += av * (float)v[i][5];
                c6 += av * (float)v[i][6];
                c7 += av * (float)v[i][7];
            }
        };
        LOADV(vA, aA, 0);
        LOADV(vB, aB, 1); COMPV(vA, aA);
        LOADV(vA, aA, 2); COMPV(vB, aB);
        LOADV(vB, aB, 3); COMPV(vA, aA);
        COMPV(vB, aB);
    }
    pc2[w4][0][lc] = make_float4(c0, c1, c2, c3);
    pc2[w4][1][lc] = make_float4(c4, c5, c6, c7);
    __syncthreads();

    // reduce 4 partials; thread t writes cols t*4..t*4+3
    if (tid < 256) {
        int hf = tid & 1, slot = tid >> 1;
        float4 s0 = pc2[0][hf][slot];
        float4 s1 = pc2[1][hf][slot];
        float4 s2 = pc2[2][hf][slot];
        float4 s3 = pc2[3][hf][slot];
        half4 o;
        o[0] = (_Float16)(s0.x + s1.x + s2.x + s3.x);
        o[1] = (_Float16)(s0.y + s1.y + s2.y + s3.y);
        o[2] = (_Float16)(s0.z + s1.z + s2.z + s3.z);
        o[3] = (_Float16)(s0.w + s1.w + s2.w + s3.w);
        *(half4*)(acat + (size_t)b * 2048 + tid * 4) = o;
    }
}

// ---------------------------------------------------------------------------
// host
// ---------------------------------------------------------------------------
extern "C" void kernel_launch(void* const* d_in, const int* in_sizes, int n_in,
                              void* d_out, int out_size, void* d_ws, size_t ws_size,
                              hipStream_t stream) {
    const float* batch_H = (const float*)d_in[0];
    const int*   text    = (const int*)d_in[1];
    const float* i2h_w   = (const float*)d_in[2];
    const float* h2h_w   = (const float*)d_in[3];
    const float* h2h_b   = (const float*)d_in[4];
    const float* score_w = (const float*)d_in[5];
    const float* W_ih    = (const float*)d_in[6];
    const float* W_hh    = (const float*)d_in[7];
    const float* b_ih    = (const float*)d_in[8];
    const float* b_hh    = (const float*)d_in[9];
    const float* gen_w   = (const float*)d_in[10];
    const float* gen_b   = (const float*)d_in[11];
    float* out = (float*)d_out;

    char* ws = (char*)d_ws;
    size_t off = 0;
    auto carve = [&](size_t bytes) -> void* {
        void* p = ws + off;
        off += (bytes + 255) & ~(size_t)255;
        return p;
    };
    _Float16* bh16   = (_Float16*)carve((size_t)BB * TT * DD * 2);   // 128 MiB
    _Float16* pH16   = (_Float16*)carve((size_t)BB * TT * HH * 2);   // 128 MiB
    _Float16* wi2h16 = (_Float16*)carve((size_t)HH * DD * 2);
    _Float16* wh2h16 = (_Float16*)carve((size_t)HH * HH * 2);
    _Float16* wcatp  = (_Float16*)carve((size_t)4 * HH * 2048 * 2);  // 16 MiB
    _Float16* wgen16 = (_Float16*)carve((size_t)VV * HH * 2);
    float*    onehT  = (float*)carve((size_t)VV * 4 * HH * 4);       // 4 MiB
    float*    bsum   = (float*)carve((size_t)4 * HH * 4);
    _Float16* acat   = (_Float16*)carve((size_t)BB * 2048 * 2);
    float*    ph_f   = (float*)carve((size_t)BB * HH * 4);
    float*    c_f    = (float*)carve((size_t)BB * HH * 4);
    _Float16* hid16  = (_Float16*)carve((size_t)SS * BB * HH * 2);   // 26 MiB

    const dim3 blk(256);

    cvt_f32_to_f16_v4<<<dim3(16384), blk, 0, stream>>>(batch_H, bh16, (long)BB * TT * DD / 4);
    cvt_f32_to_f16_v4<<<dim3(1024), blk, 0, stream>>>(i2h_w, wi2h16, (long)HH * DD / 4);
    cvt_f32_to_f16_v4<<<dim3(1024), blk, 0, stream>>>(h2h_w, wh2h16, (long)HH * HH / 4);
    cvt_f32_to_f16_v4<<<dim3(256), blk, 0, stream>>>(gen_w, wgen16, (long)VV * HH / 4);
    build_wcatp<<<dim3(4 * HH * 2048 / 256), blk, 0, stream>>>(W_ih, W_hh, wcatp);
    build_onehT<<<dim3(VV * 4 * HH / 256), blk, 0, stream>>>(W_ih, onehT);
    build_bsum<<<dim3(16), blk, 0, stream>>>(b_ih, b_hh, bsum);
    hipMemsetAsync(acat, 0, (size_t)BB * 2048 * 2, stream);  // h0 = 0
    hipMemsetAsync(c_f, 0, (size_t)BB * HH * 4, stream);     // c0 = 0

    // proj_H = batch_H @ i2h_w^T -> f16 [B*T, H], XCD-swizzled
    gemm_bt<1, 1><<<dim3(HH / 128, BB * TT / 128), blk, 0, stream>>>(
        bh16, DD, wi2h16, DD, pH16, HH, DD, nullptr);

    for (int s = 0; s < SS; ++s) {
        // proj_h = h @ h2h^T + h2h_b : [512,1024], grid (16,32) = 512 blocks
        gemm_ph<<<dim3(HH / 64, BB / 16), blk, 0, stream>>>(
            acat + 1024, 2048, wh2h16, HH, ph_f, HH, HH, h2h_b);

        attn_kernel<<<dim3(BB), dim3(512), 0, stream>>>(pH16, bh16, ph_f, score_w, acat);

        // gates GEMM + fused LSTM: [512,2048] x [4096,2048]^T, grid (64,8)
        gemm_gates<<<dim3(4 * HH / 64, BB / 64), blk, 0, stream>>>(
            acat, wcatp, bsum, onehT, text, s, c_f, acat, hid16);
    }

    // logits = hid @ gen_w^T + gen_b, remap [s,b,v] -> [b,s,v]
    gemm_bt<2, 0><<<dim3(VV / 128, SS * BB / 128), blk, 0, stream>>>(
        hid16, HH, wgen16, HH, out, VV, HH, gen_b);
}